// Round 4
// baseline (928.963 us; speedup 1.0000x reference)
//
#include <hip/hip_runtime.h>
#include <hip/hip_fp16.h>
#include <math.h>

#define NN 1000000   // nodes
#define NE 16000000  // edges
#define NB 1000000   // batch
#define NEQ (NE / 4) // edge quads
#define BN 4096      // nodes per bucket
#define NBUCK 245    // ceil(NN/BN)
#define NBUCKR 256   // buckets rounded up (245..255 empty)
#define NBLK 1024    // partition blocks
#define SSPLIT 4     // blocks per bucket in sweeps
#define CMASK 0xFFFFFu  // low-20 row mask

__device__ __forceinline__ float leaky(float v) { return v > 0.f ? v : 0.01f * v; }

__device__ __forceinline__ uint2 pack_h4(float x, float y, float z) {
    __half2 a = __floats2half2_rn(x, y);
    __half2 b = __floats2half2_rn(z, 0.f);
    uint2 u;
    u.x = *(unsigned int*)&a;
    u.y = *(unsigned int*)&b;
    return u;
}

__device__ __forceinline__ float3 unpack_h4(uint2 u) {
    __half2 a = *(__half2*)&u.x;
    __half2 b = *(__half2*)&u.y;
    float2 fa = __half22float2(a);
    return make_float3(fa.x, fa.y, __low2float(b));
}

__device__ __forceinline__ void atomicMaxF(float* addr, float val) {
    unsigned int* ia = (unsigned int*)addr;
    unsigned int old = *ia;
    while (true) {
        float f = __uint_as_float(old);
        if (f >= val) break;
        unsigned int prev = atomicCAS(ia, old, __float_as_uint(val));
        if (prev == old) break;
        old = prev;
    }
}

__global__ void init_stats(float* stats) {
    int t = threadIdx.x;
    if (t < 3) stats[t] = -1e30f;      // col maxes
    else if (t < 6) stats[t] = 0.f;    // col sum-exp
}

// ---------------- partition: count ----------------
__global__ __launch_bounds__(256) void count_kernel(const int4* __restrict__ col4,
                                                    unsigned int* __restrict__ HG) {
    __shared__ unsigned int h[NBUCKR];
    h[threadIdx.x] = 0u;
    __syncthreads();
    int stride = gridDim.x * 256;
    for (int i = blockIdx.x * 256 + threadIdx.x; i < NEQ; i += stride) {
        int4 c = col4[i];
        atomicAdd(&h[((unsigned int)c.x) >> 12], 1u);
        atomicAdd(&h[((unsigned int)c.y) >> 12], 1u);
        atomicAdd(&h[((unsigned int)c.z) >> 12], 1u);
        atomicAdd(&h[((unsigned int)c.w) >> 12], 1u);
    }
    __syncthreads();
    HG[(size_t)threadIdx.x * NBLK + blockIdx.x] = h[threadIdx.x];
}

// ---------------- scan ----------------
__global__ __launch_bounds__(256) void scan_sum(const unsigned int* __restrict__ HG,
                                                unsigned int* __restrict__ part) {
    const unsigned int* p = HG + (size_t)blockIdx.x * NBLK;
    unsigned int s = 0;
    for (int i = threadIdx.x; i < NBLK; i += 256) s += p[i];
    #pragma unroll
    for (int off = 32; off > 0; off >>= 1) s += __shfl_down(s, off);
    __shared__ unsigned int sm[4];
    int wave = threadIdx.x >> 6, lane = threadIdx.x & 63;
    if (lane == 0) sm[wave] = s;
    __syncthreads();
    if (threadIdx.x == 0) part[blockIdx.x] = sm[0] + sm[1] + sm[2] + sm[3];
}

__global__ void scan_part(unsigned int* part) {
    __shared__ unsigned int tmp[256];
    int t = threadIdx.x;
    unsigned int v = part[t];
    tmp[t] = v;
    __syncthreads();
    for (int off = 1; off < 256; off <<= 1) {
        unsigned int add = (t >= off) ? tmp[t - off] : 0u;
        __syncthreads();
        tmp[t] += add;
        __syncthreads();
    }
    part[t] = tmp[t] - v;  // exclusive
}

__global__ __launch_bounds__(256) void scan_apply(unsigned int* __restrict__ HG,
                                                  const unsigned int* __restrict__ part) {
    __shared__ unsigned int vals[NBLK];
    __shared__ unsigned int ts[256];
    int t = threadIdx.x;
    unsigned int* p = HG + (size_t)blockIdx.x * NBLK;
    for (int i = t; i < NBLK; i += 256) vals[i] = p[i];
    __syncthreads();
    unsigned int a0 = vals[4 * t], a1 = vals[4 * t + 1], a2 = vals[4 * t + 2], a3 = vals[4 * t + 3];
    unsigned int ls = a0 + a1 + a2 + a3;
    ts[t] = ls;
    __syncthreads();
    for (int off = 1; off < 256; off <<= 1) {
        unsigned int add = (t >= off) ? ts[t - off] : 0u;
        __syncthreads();
        ts[t] += add;
        __syncthreads();
    }
    unsigned int base = part[blockIdx.x] + ts[t] - ls;
    p[4 * t] = base;
    p[4 * t + 1] = base + a0;
    p[4 * t + 2] = base + a0 + a1;
    p[4 * t + 3] = base + a0 + a1 + a2;
}

// ---------------- partition: scatter records ----------------
__global__ __launch_bounds__(256) void scatter_kernel(const int4* __restrict__ row4,
                                                      const int4* __restrict__ col4,
                                                      const float4* __restrict__ w4,
                                                      const unsigned int* __restrict__ HG,
                                                      uint2* __restrict__ rec) {
    __shared__ unsigned int pos[NBUCKR];
    pos[threadIdx.x] = HG[(size_t)threadIdx.x * NBLK + blockIdx.x];
    __syncthreads();
    int stride = gridDim.x * 256;
    for (int i = blockIdx.x * 256 + threadIdx.x; i < NEQ; i += stride) {
        int4 r = row4[i];
        int4 c = col4[i];
        float4 w = w4[i];
        {
            unsigned int cu = (unsigned int)c.x;
            unsigned int p = atomicAdd(&pos[cu >> 12], 1u);
            rec[p] = make_uint2((unsigned int)r.x | ((cu & 4095u) << 20), __float_as_uint(w.x));
        }
        {
            unsigned int cu = (unsigned int)c.y;
            unsigned int p = atomicAdd(&pos[cu >> 12], 1u);
            rec[p] = make_uint2((unsigned int)r.y | ((cu & 4095u) << 20), __float_as_uint(w.y));
        }
        {
            unsigned int cu = (unsigned int)c.z;
            unsigned int p = atomicAdd(&pos[cu >> 12], 1u);
            rec[p] = make_uint2((unsigned int)r.z | ((cu & 4095u) << 20), __float_as_uint(w.z));
        }
        {
            unsigned int cu = (unsigned int)c.w;
            unsigned int p = atomicAdd(&pos[cu >> 12], 1u);
            rec[p] = make_uint2((unsigned int)r.w | ((cu & 4095u) << 20), __float_as_uint(w.w));
        }
    }
}

// ---------------- sweep 1: per-bucket deg in LDS (split x4), merge via dense atomics ------------
__global__ __launch_bounds__(512) void bucket_deg_kernel(const uint2* __restrict__ rec,
                                                         const unsigned int* __restrict__ HG,
                                                         float* __restrict__ deg_g) {
    __shared__ float degl[BN];
    int b = blockIdx.x % NBUCK;
    int sp = blockIdx.x / NBUCK;
    for (int t = threadIdx.x; t < BN; t += 512) degl[t] = 0.f;
    unsigned int s0 = HG[(size_t)b * NBLK];
    unsigned int e0 = HG[(size_t)(b + 1) * NBLK];
    unsigned int n = e0 - s0;
    unsigned int beg = s0 + (unsigned int)((unsigned long long)n * sp / SSPLIT);
    unsigned int end = s0 + (unsigned int)((unsigned long long)n * (sp + 1) / SSPLIT);
    __syncthreads();
    unsigned int i = beg + threadIdx.x;
    for (; i + 1536 < end; i += 2048) {
        uint2 r0 = rec[i], r1 = rec[i + 512], r2 = rec[i + 1024], r3 = rec[i + 1536];
        atomicAdd(&degl[r0.x >> 20], __uint_as_float(r0.y));
        atomicAdd(&degl[r1.x >> 20], __uint_as_float(r1.y));
        atomicAdd(&degl[r2.x >> 20], __uint_as_float(r2.y));
        atomicAdd(&degl[r3.x >> 20], __uint_as_float(r3.y));
    }
    for (; i < end; i += 512) {
        uint2 r0 = rec[i];
        atomicAdd(&degl[r0.x >> 20], __uint_as_float(r0.y));
    }
    __syncthreads();
    int node0 = b * BN;
    for (int t = threadIdx.x; t < BN; t += 512) {
        float v = degl[t];
        if (v != 0.f) atomicAdd(&deg_g[node0 + t], v);
    }
}

// ---------------- node epilogue 1: dinv + y = dinv*(emb@Wc) packed half4 ----------------
__global__ __launch_bounds__(256) void node1_kernel(const float* __restrict__ deg_g,
                                                    const float* __restrict__ emb,
                                                    const float* __restrict__ w_conv,
                                                    float* __restrict__ dinv,
                                                    uint2* __restrict__ y) {
    int g = blockIdx.x * 256 + threadIdx.x;
    if (g >= NN) return;
    float d = deg_g[g];
    float di = d > 0.f ? rsqrtf(d) : 0.f;
    dinv[g] = di;
    float e0 = emb[3 * g], e1 = emb[3 * g + 1], e2 = emb[3 * g + 2];
    float x0 = e0 * w_conv[0] + e1 * w_conv[3] + e2 * w_conv[6];
    float x1 = e0 * w_conv[1] + e1 * w_conv[4] + e2 * w_conv[7];
    float x2 = e0 * w_conv[2] + e1 * w_conv[5] + e2 * w_conv[8];
    y[g] = pack_h4(di * x0, di * x1, di * x2);
}

// ---------------- sweep 2: per-bucket acc in LDS (split x4), merge via dense atomics ------------
__global__ __launch_bounds__(512) void bucket_agg_kernel(const uint2* __restrict__ rec,
                                                         const unsigned int* __restrict__ HG,
                                                         const uint2* __restrict__ y,
                                                         float* __restrict__ acc_g) {
    __shared__ float acc[BN * 3];  // 48 KB
    int b = blockIdx.x % NBUCK;
    int sp = blockIdx.x / NBUCK;
    for (int t = threadIdx.x; t < BN * 3; t += 512) acc[t] = 0.f;
    unsigned int s0 = HG[(size_t)b * NBLK];
    unsigned int e0 = HG[(size_t)(b + 1) * NBLK];
    unsigned int n = e0 - s0;
    unsigned int beg = s0 + (unsigned int)((unsigned long long)n * sp / SSPLIT);
    unsigned int end = s0 + (unsigned int)((unsigned long long)n * (sp + 1) / SSPLIT);
    __syncthreads();
    unsigned int i = beg + threadIdx.x;
    for (; i + 1536 < end; i += 2048) {
        uint2 r0 = rec[i], r1 = rec[i + 512], r2 = rec[i + 1024], r3 = rec[i + 1536];
        uint2 u0 = y[r0.x & CMASK];
        uint2 u1 = y[r1.x & CMASK];
        uint2 u2 = y[r2.x & CMASK];
        uint2 u3 = y[r3.x & CMASK];
        float3 y0 = unpack_h4(u0), y1 = unpack_h4(u1), y2 = unpack_h4(u2), y3 = unpack_h4(u3);
        float w0 = __uint_as_float(r0.y), w1 = __uint_as_float(r1.y);
        float w2 = __uint_as_float(r2.y), w3 = __uint_as_float(r3.y);
        unsigned int c0 = (r0.x >> 20) * 3, c1 = (r1.x >> 20) * 3;
        unsigned int c2 = (r2.x >> 20) * 3, c3 = (r3.x >> 20) * 3;
        atomicAdd(&acc[c0 + 0], w0 * y0.x); atomicAdd(&acc[c0 + 1], w0 * y0.y); atomicAdd(&acc[c0 + 2], w0 * y0.z);
        atomicAdd(&acc[c1 + 0], w1 * y1.x); atomicAdd(&acc[c1 + 1], w1 * y1.y); atomicAdd(&acc[c1 + 2], w1 * y1.z);
        atomicAdd(&acc[c2 + 0], w2 * y2.x); atomicAdd(&acc[c2 + 1], w2 * y2.y); atomicAdd(&acc[c2 + 2], w2 * y2.z);
        atomicAdd(&acc[c3 + 0], w3 * y3.x); atomicAdd(&acc[c3 + 1], w3 * y3.y); atomicAdd(&acc[c3 + 2], w3 * y3.z);
    }
    for (; i < end; i += 512) {
        uint2 r0 = rec[i];
        float3 y0 = unpack_h4(y[r0.x & CMASK]);
        float w0 = __uint_as_float(r0.y);
        unsigned int c0 = (r0.x >> 20) * 3;
        atomicAdd(&acc[c0 + 0], w0 * y0.x); atomicAdd(&acc[c0 + 1], w0 * y0.y); atomicAdd(&acc[c0 + 2], w0 * y0.z);
    }
    __syncthreads();
    size_t base = (size_t)b * BN * 3;
    for (int t = threadIdx.x; t < BN * 3; t += 512) {
        float v = acc[t];
        if (v != 0.f) atomicAdd(&acc_g[base + t], v);
    }
}

// ---------------- node epilogue 2: xf = leaky(dinv*acc + b_conv) packed half4 ----------------
__global__ __launch_bounds__(256) void node2_kernel(const float* __restrict__ acc_g,
                                                    const float* __restrict__ dinv,
                                                    const float* __restrict__ b_conv,
                                                    uint2* __restrict__ xf) {
    int g = blockIdx.x * 256 + threadIdx.x;
    if (g >= NN) return;
    float di = dinv[g];
    float a0 = acc_g[3 * (size_t)g], a1 = acc_g[3 * (size_t)g + 1], a2 = acc_g[3 * (size_t)g + 2];
    xf[g] = pack_h4(leaky(di * a0 + b_conv[0]),
                    leaky(di * a1 + b_conv[1]),
                    leaky(di * a2 + b_conv[2]));
}

// ---------------- batch MLP + column maxes ----------------
__global__ __launch_bounds__(256) void batch_kernel(const int4* __restrict__ home4,
                                                    const int4* __restrict__ away4,
                                                    const uint2* __restrict__ xf,
                                                    const float* __restrict__ w1,
                                                    const float* __restrict__ b1,
                                                    const float* __restrict__ w3,
                                                    const float* __restrict__ b3,
                                                    float4* __restrict__ out4,
                                                    float* __restrict__ stats, int nq) {
    int i = blockIdx.x * blockDim.x + threadIdx.x;
    float m0 = -1e30f, m1 = -1e30f, m2 = -1e30f;
    if (i < nq) {
        float W1[36], B1[6], W3[18], B3[3];
        #pragma unroll
        for (int k = 0; k < 36; k++) W1[k] = w1[k];
        #pragma unroll
        for (int k = 0; k < 6; k++) B1[k] = b1[k];
        #pragma unroll
        for (int k = 0; k < 18; k++) W3[k] = w3[k];
        #pragma unroll
        for (int k = 0; k < 3; k++) B3[k] = b3[k];

        int4 hh = home4[i], aa = away4[i];
        int hs[4] = {hh.x, hh.y, hh.z, hh.w};
        int as_[4] = {aa.x, aa.y, aa.z, aa.w};
        float o[12];
        #pragma unroll
        for (int e = 0; e < 4; e++) {
            float3 xh = unpack_h4(xf[hs[e]]);
            float3 xa = unpack_h4(xf[as_[e]]);
            float h[6] = {xh.x, xh.y, xh.z, xa.x, xa.y, xa.z};
            float l1v[6];
            #pragma unroll
            for (int j = 0; j < 6; j++) {
                float s = B1[j];
                #pragma unroll
                for (int k = 0; k < 6; k++) s += h[k] * W1[k * 6 + j];
                l1v[j] = leaky(s);
            }
            float o3[3];
            #pragma unroll
            for (int j = 0; j < 3; j++) {
                float s = B3[j];
                #pragma unroll
                for (int k = 0; k < 6; k++) s += l1v[k] * W3[k * 3 + j];
                o3[j] = leaky(s);
            }
            o[3 * e + 0] = o3[0];
            o[3 * e + 1] = o3[1];
            o[3 * e + 2] = o3[2];
            m0 = fmaxf(m0, o3[0]);
            m1 = fmaxf(m1, o3[1]);
            m2 = fmaxf(m2, o3[2]);
        }
        #pragma unroll
        for (int q = 0; q < 3; q++)
            out4[3 * (size_t)i + q] = make_float4(o[4 * q], o[4 * q + 1], o[4 * q + 2], o[4 * q + 3]);
    }
    #pragma unroll
    for (int off = 32; off > 0; off >>= 1) {
        m0 = fmaxf(m0, __shfl_down(m0, off));
        m1 = fmaxf(m1, __shfl_down(m1, off));
        m2 = fmaxf(m2, __shfl_down(m2, off));
    }
    __shared__ float sm[3][4];
    int wave = threadIdx.x >> 6, lane = threadIdx.x & 63;
    if (lane == 0) { sm[0][wave] = m0; sm[1][wave] = m1; sm[2][wave] = m2; }
    __syncthreads();
    if (threadIdx.x == 0) {
        atomicMaxF(&stats[0], fmaxf(fmaxf(sm[0][0], sm[0][1]), fmaxf(sm[0][2], sm[0][3])));
        atomicMaxF(&stats[1], fmaxf(fmaxf(sm[1][0], sm[1][1]), fmaxf(sm[1][2], sm[1][3])));
        atomicMaxF(&stats[2], fmaxf(fmaxf(sm[2][0], sm[2][1]), fmaxf(sm[2][2], sm[2][3])));
    }
}

// ---------------- per-column sum of exp(v - max) ----------------
__global__ __launch_bounds__(256) void sumexp_kernel(const float4* __restrict__ out4,
                                                     float* __restrict__ stats, int nq) {
    float mx0 = stats[0], mx1 = stats[1], mx2 = stats[2];
    int i = blockIdx.x * blockDim.x + threadIdx.x;
    float s0 = 0.f, s1 = 0.f, s2 = 0.f;
    if (i < nq) {
        float4 v = out4[i];
        float vals[4] = {v.x, v.y, v.z, v.w};
        int c = (4 * i) % 3;
        #pragma unroll
        for (int e = 0; e < 4; e++) {
            float mv = (c == 0) ? mx0 : ((c == 1) ? mx1 : mx2);
            float ee = expf(vals[e] - mv);
            if (c == 0) s0 += ee; else if (c == 1) s1 += ee; else s2 += ee;
            c = (c == 2) ? 0 : (c + 1);
        }
    }
    #pragma unroll
    for (int off = 32; off > 0; off >>= 1) {
        s0 += __shfl_down(s0, off);
        s1 += __shfl_down(s1, off);
        s2 += __shfl_down(s2, off);
    }
    __shared__ float sm[3][4];
    int wave = threadIdx.x >> 6, lane = threadIdx.x & 63;
    if (lane == 0) { sm[0][wave] = s0; sm[1][wave] = s1; sm[2][wave] = s2; }
    __syncthreads();
    if (threadIdx.x == 0) {
        atomicAdd(&stats[3], sm[0][0] + sm[0][1] + sm[0][2] + sm[0][3]);
        atomicAdd(&stats[4], sm[1][0] + sm[1][1] + sm[1][2] + sm[1][3]);
        atomicAdd(&stats[5], sm[2][0] + sm[2][1] + sm[2][2] + sm[2][3]);
    }
}

// ---------------- out = h3 - max - log(sumexp), in place ----------------
__global__ __launch_bounds__(256) void final_kernel(float4* __restrict__ out4,
                                                    const float* __restrict__ stats, int nq) {
    float o0 = stats[0] + logf(stats[3]);
    float o1 = stats[1] + logf(stats[4]);
    float o2 = stats[2] + logf(stats[5]);
    int i = blockIdx.x * blockDim.x + threadIdx.x;
    if (i >= nq) return;
    float4 v = out4[i];
    float vals[4] = {v.x, v.y, v.z, v.w};
    int c = (4 * i) % 3;
    #pragma unroll
    for (int e = 0; e < 4; e++) {
        vals[e] -= (c == 0) ? o0 : ((c == 1) ? o1 : o2);
        c = (c == 2) ? 0 : (c + 1);
    }
    out4[i] = make_float4(vals[0], vals[1], vals[2], vals[3]);
}

extern "C" void kernel_launch(void* const* d_in, const int* in_sizes, int n_in,
                              void* d_out, int out_size, void* d_ws, size_t ws_size,
                              hipStream_t stream) {
    const int*   edge_index  = (const int*)d_in[0];    // [2, NE]
    const float* edge_weight = (const float*)d_in[1];  // [NE]
    const int*   home        = (const int*)d_in[2];    // [NB]
    const int*   away        = (const int*)d_in[3];    // [NB]
    const float* emb         = (const float*)d_in[4];  // [NN,3]
    const float* w_conv      = (const float*)d_in[5];  // [3,3]
    const float* b_conv      = (const float*)d_in[6];  // [3]
    const float* w1          = (const float*)d_in[7];  // [6,6]
    const float* b1          = (const float*)d_in[8];  // [6]
    const float* w3          = (const float*)d_in[9];  // [6,3]
    const float* b3          = (const float*)d_in[10]; // [3]
    float* out = (float*)d_out;

    // workspace layout (bytes)
    char* ws = (char*)d_ws;
    uint2*        rec   = (uint2*)(ws);                        // 128,000,000
    unsigned int* HG    = (unsigned int*)(ws + 128000000);     //   1,048,576
    unsigned int* part  = (unsigned int*)(ws + 129048576);     //       1,024
    float*        deg_g = (float*)(ws + 129049600);            //   4,014,080 (padded 245*4096)
    float*        dinv  = (float*)(ws + 133063680);            //   4,000,000
    uint2*        y     = (uint2*)(ws + 137063680);            //   8,000,000 (half4)
    float*        acc_g = (float*)(ws + 145063680);            //  12,042,240 (padded 245*4096*3)
    uint2*        xf    = (uint2*)(ws + 157105920);            //   8,000,000 (half4)
    float*        stats = (float*)(ws + 165105920);            //          24

    const int* row = edge_index;
    const int* col = edge_index + NE;

    init_stats<<<1, 64, 0, stream>>>(stats);
    hipMemsetAsync(deg_g, 0, 4014080, stream);
    hipMemsetAsync(acc_g, 0, 12042240, stream);

    // partition edges by col>>12 into 245 buckets of 4096 nodes
    count_kernel<<<NBLK, 256, 0, stream>>>((const int4*)col, HG);
    scan_sum<<<NBUCKR, 256, 0, stream>>>(HG, part);
    scan_part<<<1, 256, 0, stream>>>(part);
    scan_apply<<<NBUCKR, 256, 0, stream>>>(HG, part);
    scatter_kernel<<<NBLK, 256, 0, stream>>>((const int4*)row, (const int4*)col,
                                             (const float4*)edge_weight, HG, rec);

    // bucketed LDS accumulation, 4 split-blocks per bucket
    bucket_deg_kernel<<<NBUCK * SSPLIT, 512, 0, stream>>>(rec, HG, deg_g);
    node1_kernel<<<(NN + 255) / 256, 256, 0, stream>>>(deg_g, emb, w_conv, dinv, y);
    bucket_agg_kernel<<<NBUCK * SSPLIT, 512, 0, stream>>>(rec, HG, y, acc_g);
    node2_kernel<<<(NN + 255) / 256, 256, 0, stream>>>(acc_g, dinv, b_conv, xf);

    // MLP + log-softmax over dim 0
    const int BQ = NB / 4;
    const int OQ = (NB * 3) / 4;
    batch_kernel<<<(BQ + 255) / 256, 256, 0, stream>>>((const int4*)home, (const int4*)away, xf,
                                                       w1, b1, w3, b3, (float4*)out, stats, BQ);
    sumexp_kernel<<<(OQ + 255) / 256, 256, 0, stream>>>((const float4*)out, stats, OQ);
    final_kernel<<<(OQ + 255) / 256, 256, 0, stream>>>((float4*)out, stats, OQ);
}

// Round 5
// 918.174 us; speedup vs baseline: 1.0118x; 1.0118x over previous
//
#include <hip/hip_runtime.h>
#include <math.h>

#define NN 1000000   // nodes
#define NE 16000000  // edges
#define NB 1000000   // batch
#define NEQ (NE / 4) // edge quads
#define BN 4096      // nodes per bucket
#define NBUCK 245    // ceil(NN/BN)
#define NBUCKR 256   // buckets rounded up
#define NBLK 1024    // partition blocks
#define SSPLIT 4     // blocks per bucket in sweeps
#define CMASK 0xFFFFFu  // low-20 row mask

typedef int   i32x4 __attribute__((ext_vector_type(4)));
typedef float f32x4 __attribute__((ext_vector_type(4)));

__device__ __forceinline__ float leaky(float v) { return v > 0.f ? v : 0.01f * v; }

// ---- 4-byte block-float: 5-bit shared exponent + 3 x 9-bit signed mantissa ----
__device__ __forceinline__ unsigned int pack_bf32(float x, float y, float z) {
    float m = fmaxf(fmaxf(fabsf(x), fabsf(y)), fabsf(z));
    int ex = ((int)(__float_as_uint(m) >> 23) & 0xFF) - 126;  // 2^ex >= m
    ex = min(max(ex, -20), 11);
    float scale = __uint_as_float((unsigned int)(135 - ex) << 23);  // 256 * 2^-ex
    int qx = min(max(__float2int_rn(x * scale), -255), 255);
    int qy = min(max(__float2int_rn(y * scale), -255), 255);
    int qz = min(max(__float2int_rn(z * scale), -255), 255);
    return ((unsigned int)(qx & 0x1FF)) | ((unsigned int)(qy & 0x1FF) << 9) |
           ((unsigned int)(qz & 0x1FF) << 18) | ((unsigned int)(ex + 20) << 27);
}

__device__ __forceinline__ float3 unpack_bf32(unsigned int u) {
    int qx = ((int)(u << 23)) >> 23;
    int qy = ((int)(u << 14)) >> 23;
    int qz = ((int)(u << 5)) >> 23;
    int ex = (int)(u >> 27) - 20;
    float s = __uint_as_float((unsigned int)(ex + 119) << 23);  // 2^(ex-8)
    return make_float3(qx * s, qy * s, qz * s);
}

__device__ __forceinline__ void atomicMaxF(float* addr, float val) {
    unsigned int* ia = (unsigned int*)addr;
    unsigned int old = *ia;
    while (true) {
        float f = __uint_as_float(old);
        if (f >= val) break;
        unsigned int prev = atomicCAS(ia, old, __float_as_uint(val));
        if (prev == old) break;
        old = prev;
    }
}

__global__ void init_stats(float* stats) {
    int t = threadIdx.x;
    if (t < 3) stats[t] = -1e30f;      // col maxes
    else if (t < 6) stats[t] = 0.f;    // col sum-exp
}

// ---------------- partition: count ----------------
__global__ __launch_bounds__(256) void count_kernel(const i32x4* __restrict__ col4,
                                                    unsigned int* __restrict__ HG) {
    __shared__ unsigned int h[NBUCKR];
    h[threadIdx.x] = 0u;
    __syncthreads();
    int stride = gridDim.x * 256;
    for (int i = blockIdx.x * 256 + threadIdx.x; i < NEQ; i += stride) {
        i32x4 c = __builtin_nontemporal_load(col4 + i);
        atomicAdd(&h[((unsigned int)c.x) >> 12], 1u);
        atomicAdd(&h[((unsigned int)c.y) >> 12], 1u);
        atomicAdd(&h[((unsigned int)c.z) >> 12], 1u);
        atomicAdd(&h[((unsigned int)c.w) >> 12], 1u);
    }
    __syncthreads();
    HG[(size_t)threadIdx.x * NBLK + blockIdx.x] = h[threadIdx.x];
}

// ---------------- scan ----------------
__global__ __launch_bounds__(256) void scan_sum(const unsigned int* __restrict__ HG,
                                                unsigned int* __restrict__ part) {
    const unsigned int* p = HG + (size_t)blockIdx.x * NBLK;
    unsigned int s = 0;
    for (int i = threadIdx.x; i < NBLK; i += 256) s += p[i];
    #pragma unroll
    for (int off = 32; off > 0; off >>= 1) s += __shfl_down(s, off);
    __shared__ unsigned int sm[4];
    int wave = threadIdx.x >> 6, lane = threadIdx.x & 63;
    if (lane == 0) sm[wave] = s;
    __syncthreads();
    if (threadIdx.x == 0) part[blockIdx.x] = sm[0] + sm[1] + sm[2] + sm[3];
}

__global__ void scan_part(unsigned int* part) {
    __shared__ unsigned int tmp[256];
    int t = threadIdx.x;
    unsigned int v = part[t];
    tmp[t] = v;
    __syncthreads();
    for (int off = 1; off < 256; off <<= 1) {
        unsigned int add = (t >= off) ? tmp[t - off] : 0u;
        __syncthreads();
        tmp[t] += add;
        __syncthreads();
    }
    part[t] = tmp[t] - v;  // exclusive
}

__global__ __launch_bounds__(256) void scan_apply(unsigned int* __restrict__ HG,
                                                  const unsigned int* __restrict__ part) {
    __shared__ unsigned int vals[NBLK];
    __shared__ unsigned int ts[256];
    int t = threadIdx.x;
    unsigned int* p = HG + (size_t)blockIdx.x * NBLK;
    for (int i = t; i < NBLK; i += 256) vals[i] = p[i];
    __syncthreads();
    unsigned int a0 = vals[4 * t], a1 = vals[4 * t + 1], a2 = vals[4 * t + 2], a3 = vals[4 * t + 3];
    unsigned int ls = a0 + a1 + a2 + a3;
    ts[t] = ls;
    __syncthreads();
    for (int off = 1; off < 256; off <<= 1) {
        unsigned int add = (t >= off) ? ts[t - off] : 0u;
        __syncthreads();
        ts[t] += add;
        __syncthreads();
    }
    unsigned int base = part[blockIdx.x] + ts[t] - ls;
    p[4 * t] = base;
    p[4 * t + 1] = base + a0;
    p[4 * t + 2] = base + a0 + a1;
    p[4 * t + 3] = base + a0 + a1 + a2;
}

// ---------------- partition: scatter records ----------------
__global__ __launch_bounds__(256) void scatter_kernel(const i32x4* __restrict__ row4,
                                                      const i32x4* __restrict__ col4,
                                                      const f32x4* __restrict__ w4,
                                                      const unsigned int* __restrict__ HG,
                                                      uint2* __restrict__ rec) {
    __shared__ unsigned int pos[NBUCKR];
    pos[threadIdx.x] = HG[(size_t)threadIdx.x * NBLK + blockIdx.x];
    __syncthreads();
    int stride = gridDim.x * 256;
    for (int i = blockIdx.x * 256 + threadIdx.x; i < NEQ; i += stride) {
        i32x4 r = __builtin_nontemporal_load(row4 + i);
        i32x4 c = __builtin_nontemporal_load(col4 + i);
        f32x4 w = __builtin_nontemporal_load(w4 + i);
        {
            unsigned int cu = (unsigned int)c.x;
            unsigned int p = atomicAdd(&pos[cu >> 12], 1u);
            rec[p] = make_uint2((unsigned int)r.x | ((cu & 4095u) << 20), __float_as_uint(w.x));
        }
        {
            unsigned int cu = (unsigned int)c.y;
            unsigned int p = atomicAdd(&pos[cu >> 12], 1u);
            rec[p] = make_uint2((unsigned int)r.y | ((cu & 4095u) << 20), __float_as_uint(w.y));
        }
        {
            unsigned int cu = (unsigned int)c.z;
            unsigned int p = atomicAdd(&pos[cu >> 12], 1u);
            rec[p] = make_uint2((unsigned int)r.z | ((cu & 4095u) << 20), __float_as_uint(w.z));
        }
        {
            unsigned int cu = (unsigned int)c.w;
            unsigned int p = atomicAdd(&pos[cu >> 12], 1u);
            rec[p] = make_uint2((unsigned int)r.w | ((cu & 4095u) << 20), __float_as_uint(w.w));
        }
    }
}

// ---------------- sweep 1: per-bucket deg in LDS (split x4), dense atomic merge ----------------
__global__ __launch_bounds__(512) void bucket_deg_kernel(const unsigned long long* __restrict__ rec,
                                                         const unsigned int* __restrict__ HG,
                                                         float* __restrict__ deg_g) {
    __shared__ float degl[BN];
    int b = blockIdx.x % NBUCK;
    int sp = blockIdx.x / NBUCK;
    for (int t = threadIdx.x; t < BN; t += 512) degl[t] = 0.f;
    unsigned int s0 = HG[(size_t)b * NBLK];
    unsigned int e0 = HG[(size_t)(b + 1) * NBLK];
    unsigned int n = e0 - s0;
    unsigned int beg = s0 + (unsigned int)((unsigned long long)n * sp / SSPLIT);
    unsigned int end = s0 + (unsigned int)((unsigned long long)n * (sp + 1) / SSPLIT);
    __syncthreads();
    unsigned int i = beg + threadIdx.x;
    for (; i + 3584 < end; i += 4096) {
        unsigned long long r[8];
        #pragma unroll
        for (int k = 0; k < 8; k++) r[k] = __builtin_nontemporal_load(rec + i + k * 512);
        #pragma unroll
        for (int k = 0; k < 8; k++)
            atomicAdd(&degl[((unsigned int)r[k]) >> 20], __uint_as_float((unsigned int)(r[k] >> 32)));
    }
    for (; i < end; i += 512) {
        unsigned long long r0 = __builtin_nontemporal_load(rec + i);
        atomicAdd(&degl[((unsigned int)r0) >> 20], __uint_as_float((unsigned int)(r0 >> 32)));
    }
    __syncthreads();
    int node0 = b * BN;
    for (int t = threadIdx.x; t < BN; t += 512) {
        float v = degl[t];
        if (v != 0.f) atomicAdd(&deg_g[node0 + t], v);
    }
}

// ---------------- node epilogue 1: dinv + y = dinv*(emb@Wc) packed block-float ----------------
__global__ __launch_bounds__(256) void node1_kernel(const float* __restrict__ deg_g,
                                                    const float* __restrict__ emb,
                                                    const float* __restrict__ w_conv,
                                                    float* __restrict__ dinv,
                                                    unsigned int* __restrict__ y) {
    int g = blockIdx.x * 256 + threadIdx.x;
    if (g >= NN) return;
    float d = deg_g[g];
    float di = d > 0.f ? rsqrtf(d) : 0.f;
    dinv[g] = di;
    float e0 = emb[3 * g], e1 = emb[3 * g + 1], e2 = emb[3 * g + 2];
    float x0 = e0 * w_conv[0] + e1 * w_conv[3] + e2 * w_conv[6];
    float x1 = e0 * w_conv[1] + e1 * w_conv[4] + e2 * w_conv[7];
    float x2 = e0 * w_conv[2] + e1 * w_conv[5] + e2 * w_conv[8];
    y[g] = pack_bf32(di * x0, di * x1, di * x2);
}

// ---------------- sweep 2: per-bucket acc in LDS (split x4), dense atomic merge ----------------
__global__ __launch_bounds__(512) void bucket_agg_kernel(const unsigned long long* __restrict__ rec,
                                                         const unsigned int* __restrict__ HG,
                                                         const unsigned int* __restrict__ y,
                                                         float* __restrict__ acc_g) {
    __shared__ float acc[BN * 3];  // 48 KB
    int b = blockIdx.x % NBUCK;
    int sp = blockIdx.x / NBUCK;
    for (int t = threadIdx.x; t < BN * 3; t += 512) acc[t] = 0.f;
    unsigned int s0 = HG[(size_t)b * NBLK];
    unsigned int e0 = HG[(size_t)(b + 1) * NBLK];
    unsigned int n = e0 - s0;
    unsigned int beg = s0 + (unsigned int)((unsigned long long)n * sp / SSPLIT);
    unsigned int end = s0 + (unsigned int)((unsigned long long)n * (sp + 1) / SSPLIT);
    __syncthreads();
    unsigned int i = beg + threadIdx.x;
    for (; i + 3584 < end; i += 4096) {
        unsigned long long r[8];
        #pragma unroll
        for (int k = 0; k < 8; k++) r[k] = __builtin_nontemporal_load(rec + i + k * 512);
        unsigned int yu[8];
        #pragma unroll
        for (int k = 0; k < 8; k++) yu[k] = y[((unsigned int)r[k]) & CMASK];
        #pragma unroll
        for (int k = 0; k < 8; k++) {
            float w = __uint_as_float((unsigned int)(r[k] >> 32));
            float3 yv = unpack_bf32(yu[k]);
            unsigned int c = (((unsigned int)r[k]) >> 20) * 3;
            atomicAdd(&acc[c + 0], w * yv.x);
            atomicAdd(&acc[c + 1], w * yv.y);
            atomicAdd(&acc[c + 2], w * yv.z);
        }
    }
    for (; i < end; i += 512) {
        unsigned long long r0 = __builtin_nontemporal_load(rec + i);
        float w = __uint_as_float((unsigned int)(r0 >> 32));
        float3 yv = unpack_bf32(y[((unsigned int)r0) & CMASK]);
        unsigned int c = (((unsigned int)r0) >> 20) * 3;
        atomicAdd(&acc[c + 0], w * yv.x);
        atomicAdd(&acc[c + 1], w * yv.y);
        atomicAdd(&acc[c + 2], w * yv.z);
    }
    __syncthreads();
    size_t base = (size_t)b * BN * 3;
    for (int t = threadIdx.x; t < BN * 3; t += 512) {
        float v = acc[t];
        if (v != 0.f) atomicAdd(&acc_g[base + t], v);
    }
}

// ---------------- node epilogue 2: xf = leaky(dinv*acc + b_conv) packed block-float -------------
__global__ __launch_bounds__(256) void node2_kernel(const float* __restrict__ acc_g,
                                                    const float* __restrict__ dinv,
                                                    const float* __restrict__ b_conv,
                                                    unsigned int* __restrict__ xf) {
    int g = blockIdx.x * 256 + threadIdx.x;
    if (g >= NN) return;
    float di = dinv[g];
    float a0 = acc_g[3 * (size_t)g], a1 = acc_g[3 * (size_t)g + 1], a2 = acc_g[3 * (size_t)g + 2];
    xf[g] = pack_bf32(leaky(di * a0 + b_conv[0]),
                      leaky(di * a1 + b_conv[1]),
                      leaky(di * a2 + b_conv[2]));
}

// ---------------- batch MLP + column maxes ----------------
__global__ __launch_bounds__(256) void batch_kernel(const i32x4* __restrict__ home4,
                                                    const i32x4* __restrict__ away4,
                                                    const unsigned int* __restrict__ xf,
                                                    const float* __restrict__ w1,
                                                    const float* __restrict__ b1,
                                                    const float* __restrict__ w3,
                                                    const float* __restrict__ b3,
                                                    float4* __restrict__ out4,
                                                    float* __restrict__ stats, int nq) {
    int i = blockIdx.x * blockDim.x + threadIdx.x;
    float m0 = -1e30f, m1 = -1e30f, m2 = -1e30f;
    if (i < nq) {
        float W1[36], B1[6], W3[18], B3[3];
        #pragma unroll
        for (int k = 0; k < 36; k++) W1[k] = w1[k];
        #pragma unroll
        for (int k = 0; k < 6; k++) B1[k] = b1[k];
        #pragma unroll
        for (int k = 0; k < 18; k++) W3[k] = w3[k];
        #pragma unroll
        for (int k = 0; k < 3; k++) B3[k] = b3[k];

        i32x4 hh = __builtin_nontemporal_load(home4 + i);
        i32x4 aa = __builtin_nontemporal_load(away4 + i);
        int hs[4] = {hh.x, hh.y, hh.z, hh.w};
        int as_[4] = {aa.x, aa.y, aa.z, aa.w};
        float o[12];
        #pragma unroll
        for (int e = 0; e < 4; e++) {
            float3 xh = unpack_bf32(xf[hs[e]]);
            float3 xa = unpack_bf32(xf[as_[e]]);
            float h[6] = {xh.x, xh.y, xh.z, xa.x, xa.y, xa.z};
            float l1v[6];
            #pragma unroll
            for (int j = 0; j < 6; j++) {
                float s = B1[j];
                #pragma unroll
                for (int k = 0; k < 6; k++) s += h[k] * W1[k * 6 + j];
                l1v[j] = leaky(s);
            }
            float o3[3];
            #pragma unroll
            for (int j = 0; j < 3; j++) {
                float s = B3[j];
                #pragma unroll
                for (int k = 0; k < 6; k++) s += l1v[k] * W3[k * 3 + j];
                o3[j] = leaky(s);
            }
            o[3 * e + 0] = o3[0];
            o[3 * e + 1] = o3[1];
            o[3 * e + 2] = o3[2];
            m0 = fmaxf(m0, o3[0]);
            m1 = fmaxf(m1, o3[1]);
            m2 = fmaxf(m2, o3[2]);
        }
        #pragma unroll
        for (int q = 0; q < 3; q++)
            out4[3 * (size_t)i + q] = make_float4(o[4 * q], o[4 * q + 1], o[4 * q + 2], o[4 * q + 3]);
    }
    #pragma unroll
    for (int off = 32; off > 0; off >>= 1) {
        m0 = fmaxf(m0, __shfl_down(m0, off));
        m1 = fmaxf(m1, __shfl_down(m1, off));
        m2 = fmaxf(m2, __shfl_down(m2, off));
    }
    __shared__ float sm[3][4];
    int wave = threadIdx.x >> 6, lane = threadIdx.x & 63;
    if (lane == 0) { sm[0][wave] = m0; sm[1][wave] = m1; sm[2][wave] = m2; }
    __syncthreads();
    if (threadIdx.x == 0) {
        atomicMaxF(&stats[0], fmaxf(fmaxf(sm[0][0], sm[0][1]), fmaxf(sm[0][2], sm[0][3])));
        atomicMaxF(&stats[1], fmaxf(fmaxf(sm[1][0], sm[1][1]), fmaxf(sm[1][2], sm[1][3])));
        atomicMaxF(&stats[2], fmaxf(fmaxf(sm[2][0], sm[2][1]), fmaxf(sm[2][2], sm[2][3])));
    }
}

// ---------------- per-column sum of exp(v - max) ----------------
__global__ __launch_bounds__(256) void sumexp_kernel(const float4* __restrict__ out4,
                                                     float* __restrict__ stats, int nq) {
    float mx0 = stats[0], mx1 = stats[1], mx2 = stats[2];
    int i = blockIdx.x * blockDim.x + threadIdx.x;
    float s0 = 0.f, s1 = 0.f, s2 = 0.f;
    if (i < nq) {
        float4 v = out4[i];
        float vals[4] = {v.x, v.y, v.z, v.w};
        int c = (4 * i) % 3;
        #pragma unroll
        for (int e = 0; e < 4; e++) {
            float mv = (c == 0) ? mx0 : ((c == 1) ? mx1 : mx2);
            float ee = expf(vals[e] - mv);
            if (c == 0) s0 += ee; else if (c == 1) s1 += ee; else s2 += ee;
            c = (c == 2) ? 0 : (c + 1);
        }
    }
    #pragma unroll
    for (int off = 32; off > 0; off >>= 1) {
        s0 += __shfl_down(s0, off);
        s1 += __shfl_down(s1, off);
        s2 += __shfl_down(s2, off);
    }
    __shared__ float sm[3][4];
    int wave = threadIdx.x >> 6, lane = threadIdx.x & 63;
    if (lane == 0) { sm[0][wave] = s0; sm[1][wave] = s1; sm[2][wave] = s2; }
    __syncthreads();
    if (threadIdx.x == 0) {
        atomicAdd(&stats[3], sm[0][0] + sm[0][1] + sm[0][2] + sm[0][3]);
        atomicAdd(&stats[4], sm[1][0] + sm[1][1] + sm[1][2] + sm[1][3]);
        atomicAdd(&stats[5], sm[2][0] + sm[2][1] + sm[2][2] + sm[2][3]);
    }
}

// ---------------- out = h3 - max - log(sumexp), in place ----------------
__global__ __launch_bounds__(256) void final_kernel(float4* __restrict__ out4,
                                                    const float* __restrict__ stats, int nq) {
    float o0 = stats[0] + logf(stats[3]);
    float o1 = stats[1] + logf(stats[4]);
    float o2 = stats[2] + logf(stats[5]);
    int i = blockIdx.x * blockDim.x + threadIdx.x;
    if (i >= nq) return;
    float4 v = out4[i];
    float vals[4] = {v.x, v.y, v.z, v.w};
    int c = (4 * i) % 3;
    #pragma unroll
    for (int e = 0; e < 4; e++) {
        vals[e] -= (c == 0) ? o0 : ((c == 1) ? o1 : o2);
        c = (c == 2) ? 0 : (c + 1);
    }
    out4[i] = make_float4(vals[0], vals[1], vals[2], vals[3]);
}

extern "C" void kernel_launch(void* const* d_in, const int* in_sizes, int n_in,
                              void* d_out, int out_size, void* d_ws, size_t ws_size,
                              hipStream_t stream) {
    const int*   edge_index  = (const int*)d_in[0];    // [2, NE]
    const float* edge_weight = (const float*)d_in[1];  // [NE]
    const int*   home        = (const int*)d_in[2];    // [NB]
    const int*   away        = (const int*)d_in[3];    // [NB]
    const float* emb         = (const float*)d_in[4];  // [NN,3]
    const float* w_conv      = (const float*)d_in[5];  // [3,3]
    const float* b_conv      = (const float*)d_in[6];  // [3]
    const float* w1          = (const float*)d_in[7];  // [6,6]
    const float* b1          = (const float*)d_in[8];  // [6]
    const float* w3          = (const float*)d_in[9];  // [6,3]
    const float* b3          = (const float*)d_in[10]; // [3]
    float* out = (float*)d_out;

    // workspace layout (bytes)
    char* ws = (char*)d_ws;
    uint2*        rec   = (uint2*)(ws);                        // 128,000,000
    unsigned int* HG    = (unsigned int*)(ws + 128000000);     //   1,048,576
    unsigned int* part  = (unsigned int*)(ws + 129048576);     //       1,024
    float*        deg_g = (float*)(ws + 129049600);            //   4,014,080 (245*4096*4)
    float*        dinv  = (float*)(ws + 133063680);            //   4,000,000
    unsigned int* y     = (unsigned int*)(ws + 137063680);     //   4,000,000 (block-float)
    float*        acc_g = (float*)(ws + 141063680);            //  12,042,240 (245*4096*3*4)
    unsigned int* xf    = (unsigned int*)(ws + 153105920);     //   4,000,000 (block-float)
    float*        stats = (float*)(ws + 157105920);            //          24

    const int* row = edge_index;
    const int* col = edge_index + NE;

    init_stats<<<1, 64, 0, stream>>>(stats);
    hipMemsetAsync(deg_g, 0, 4014080, stream);
    hipMemsetAsync(acc_g, 0, 12042240, stream);

    // partition edges by col>>12 into 245 buckets of 4096 nodes
    count_kernel<<<NBLK, 256, 0, stream>>>((const i32x4*)col, HG);
    scan_sum<<<NBUCKR, 256, 0, stream>>>(HG, part);
    scan_part<<<1, 256, 0, stream>>>(part);
    scan_apply<<<NBUCKR, 256, 0, stream>>>(HG, part);
    scatter_kernel<<<NBLK, 256, 0, stream>>>((const i32x4*)row, (const i32x4*)col,
                                             (const f32x4*)edge_weight, HG, rec);

    // bucketed LDS accumulation, 4 split-blocks per bucket
    bucket_deg_kernel<<<NBUCK * SSPLIT, 512, 0, stream>>>((const unsigned long long*)rec, HG, deg_g);
    node1_kernel<<<(NN + 255) / 256, 256, 0, stream>>>(deg_g, emb, w_conv, dinv, y);
    bucket_agg_kernel<<<NBUCK * SSPLIT, 512, 0, stream>>>((const unsigned long long*)rec, HG, y, acc_g);
    node2_kernel<<<(NN + 255) / 256, 256, 0, stream>>>(acc_g, dinv, b_conv, xf);

    // MLP + log-softmax over dim 0
    const int BQ = NB / 4;
    const int OQ = (NB * 3) / 4;
    batch_kernel<<<(BQ + 255) / 256, 256, 0, stream>>>((const i32x4*)home, (const i32x4*)away, xf,
                                                       w1, b1, w3, b3, (float4*)out, stats, BQ);
    sumexp_kernel<<<(OQ + 255) / 256, 256, 0, stream>>>((const float4*)out, stats, OQ);
    final_kernel<<<(OQ + 255) / 256, 256, 0, stream>>>((float4*)out, stats, OQ);
}

// Round 6
// 907.290 us; speedup vs baseline: 1.0239x; 1.0120x over previous
//
#include <hip/hip_runtime.h>
#include <math.h>

#define NN 1000000   // nodes
#define NE 16000000  // edges
#define NB 1000000   // batch
#define NEQ (NE / 4) // edge quads
#define BN 4096      // nodes per bucket
#define NBUCK 245    // ceil(NN/BN)
#define NBUCKR 256   // buckets rounded up
#define NBLK 1024    // partition blocks
#define SSPLIT 4     // blocks per bucket in sweeps
#define CMASK 0xFFFFFu  // low-20 row mask

typedef int   i32x4 __attribute__((ext_vector_type(4)));
typedef float f32x4 __attribute__((ext_vector_type(4)));

__device__ __forceinline__ float leaky(float v) { return v > 0.f ? v : 0.01f * v; }

// native HW fp32 atomic (ds_add_f32 / global_atomic_add_f32); plain atomicAdd(float*)
// compiles to a CAS loop without unsafe-fp-atomics
#define ATOMF(p, v) unsafeAtomicAdd((p), (v))

// ---- 4-byte block-float: 5-bit shared exponent + 3 x 9-bit signed mantissa ----
__device__ __forceinline__ unsigned int pack_bf32(float x, float y, float z) {
    float m = fmaxf(fmaxf(fabsf(x), fabsf(y)), fabsf(z));
    int ex = ((int)(__float_as_uint(m) >> 23) & 0xFF) - 126;  // 2^ex >= m
    ex = min(max(ex, -20), 11);
    float scale = __uint_as_float((unsigned int)(135 - ex) << 23);  // 256 * 2^-ex
    int qx = min(max(__float2int_rn(x * scale), -255), 255);
    int qy = min(max(__float2int_rn(y * scale), -255), 255);
    int qz = min(max(__float2int_rn(z * scale), -255), 255);
    return ((unsigned int)(qx & 0x1FF)) | ((unsigned int)(qy & 0x1FF) << 9) |
           ((unsigned int)(qz & 0x1FF) << 18) | ((unsigned int)(ex + 20) << 27);
}

__device__ __forceinline__ float3 unpack_bf32(unsigned int u) {
    int qx = ((int)(u << 23)) >> 23;
    int qy = ((int)(u << 14)) >> 23;
    int qz = ((int)(u << 5)) >> 23;
    int ex = (int)(u >> 27) - 20;
    float s = __uint_as_float((unsigned int)(ex + 119) << 23);  // 2^(ex-8)
    return make_float3(qx * s, qy * s, qz * s);
}

__device__ __forceinline__ void atomicMaxF(float* addr, float val) {
    unsigned int* ia = (unsigned int*)addr;
    unsigned int old = *ia;
    while (true) {
        float f = __uint_as_float(old);
        if (f >= val) break;
        unsigned int prev = atomicCAS(ia, old, __float_as_uint(val));
        if (prev == old) break;
        old = prev;
    }
}

__global__ void init_stats(float* stats) {
    int t = threadIdx.x;
    if (t < 3) stats[t] = -1e30f;      // col maxes
    else if (t < 6) stats[t] = 0.f;    // col sum-exp
}

// ---------------- partition: count ----------------
__global__ __launch_bounds__(256) void count_kernel(const i32x4* __restrict__ col4,
                                                    unsigned int* __restrict__ HG) {
    __shared__ unsigned int h[NBUCKR];
    h[threadIdx.x] = 0u;
    __syncthreads();
    int stride = gridDim.x * 256;
    for (int i = blockIdx.x * 256 + threadIdx.x; i < NEQ; i += stride) {
        i32x4 c = __builtin_nontemporal_load(col4 + i);
        atomicAdd(&h[((unsigned int)c.x) >> 12], 1u);
        atomicAdd(&h[((unsigned int)c.y) >> 12], 1u);
        atomicAdd(&h[((unsigned int)c.z) >> 12], 1u);
        atomicAdd(&h[((unsigned int)c.w) >> 12], 1u);
    }
    __syncthreads();
    HG[(size_t)threadIdx.x * NBLK + blockIdx.x] = h[threadIdx.x];
}

// ---------------- scan ----------------
__global__ __launch_bounds__(256) void scan_sum(const unsigned int* __restrict__ HG,
                                                unsigned int* __restrict__ part) {
    const unsigned int* p = HG + (size_t)blockIdx.x * NBLK;
    unsigned int s = 0;
    for (int i = threadIdx.x; i < NBLK; i += 256) s += p[i];
    #pragma unroll
    for (int off = 32; off > 0; off >>= 1) s += __shfl_down(s, off);
    __shared__ unsigned int sm[4];
    int wave = threadIdx.x >> 6, lane = threadIdx.x & 63;
    if (lane == 0) sm[wave] = s;
    __syncthreads();
    if (threadIdx.x == 0) part[blockIdx.x] = sm[0] + sm[1] + sm[2] + sm[3];
}

__global__ void scan_part(unsigned int* part) {
    __shared__ unsigned int tmp[256];
    int t = threadIdx.x;
    unsigned int v = part[t];
    tmp[t] = v;
    __syncthreads();
    for (int off = 1; off < 256; off <<= 1) {
        unsigned int add = (t >= off) ? tmp[t - off] : 0u;
        __syncthreads();
        tmp[t] += add;
        __syncthreads();
    }
    part[t] = tmp[t] - v;  // exclusive
}

__global__ __launch_bounds__(256) void scan_apply(unsigned int* __restrict__ HG,
                                                  const unsigned int* __restrict__ part) {
    __shared__ unsigned int vals[NBLK];
    __shared__ unsigned int ts[256];
    int t = threadIdx.x;
    unsigned int* p = HG + (size_t)blockIdx.x * NBLK;
    for (int i = t; i < NBLK; i += 256) vals[i] = p[i];
    __syncthreads();
    unsigned int a0 = vals[4 * t], a1 = vals[4 * t + 1], a2 = vals[4 * t + 2], a3 = vals[4 * t + 3];
    unsigned int ls = a0 + a1 + a2 + a3;
    ts[t] = ls;
    __syncthreads();
    for (int off = 1; off < 256; off <<= 1) {
        unsigned int add = (t >= off) ? ts[t - off] : 0u;
        __syncthreads();
        ts[t] += add;
        __syncthreads();
    }
    unsigned int base = part[blockIdx.x] + ts[t] - ls;
    p[4 * t] = base;
    p[4 * t + 1] = base + a0;
    p[4 * t + 2] = base + a0 + a1;
    p[4 * t + 3] = base + a0 + a1 + a2;
}

// ---------------- partition: scatter records ----------------
__global__ __launch_bounds__(256) void scatter_kernel(const i32x4* __restrict__ row4,
                                                      const i32x4* __restrict__ col4,
                                                      const f32x4* __restrict__ w4,
                                                      const unsigned int* __restrict__ HG,
                                                      uint2* __restrict__ rec) {
    __shared__ unsigned int pos[NBUCKR];
    pos[threadIdx.x] = HG[(size_t)threadIdx.x * NBLK + blockIdx.x];
    __syncthreads();
    int stride = gridDim.x * 256;
    for (int i = blockIdx.x * 256 + threadIdx.x; i < NEQ; i += stride) {
        i32x4 r = __builtin_nontemporal_load(row4 + i);
        i32x4 c = __builtin_nontemporal_load(col4 + i);
        f32x4 w = __builtin_nontemporal_load(w4 + i);
        {
            unsigned int cu = (unsigned int)c.x;
            unsigned int p = atomicAdd(&pos[cu >> 12], 1u);
            rec[p] = make_uint2((unsigned int)r.x | ((cu & 4095u) << 20), __float_as_uint(w.x));
        }
        {
            unsigned int cu = (unsigned int)c.y;
            unsigned int p = atomicAdd(&pos[cu >> 12], 1u);
            rec[p] = make_uint2((unsigned int)r.y | ((cu & 4095u) << 20), __float_as_uint(w.y));
        }
        {
            unsigned int cu = (unsigned int)c.z;
            unsigned int p = atomicAdd(&pos[cu >> 12], 1u);
            rec[p] = make_uint2((unsigned int)r.z | ((cu & 4095u) << 20), __float_as_uint(w.z));
        }
        {
            unsigned int cu = (unsigned int)c.w;
            unsigned int p = atomicAdd(&pos[cu >> 12], 1u);
            rec[p] = make_uint2((unsigned int)r.w | ((cu & 4095u) << 20), __float_as_uint(w.w));
        }
    }
}

// ---------------- sweep 1: per-bucket deg in LDS (split x4), dense atomic merge ----------------
__global__ __launch_bounds__(512) void bucket_deg_kernel(const unsigned long long* __restrict__ rec,
                                                         const unsigned int* __restrict__ HG,
                                                         float* __restrict__ deg_g) {
    __shared__ float degl[BN];
    int b = blockIdx.x % NBUCK;
    int sp = blockIdx.x / NBUCK;
    for (int t = threadIdx.x; t < BN; t += 512) degl[t] = 0.f;
    unsigned int s0 = HG[(size_t)b * NBLK];
    unsigned int e0 = HG[(size_t)(b + 1) * NBLK];
    unsigned int n = e0 - s0;
    unsigned int beg = s0 + (unsigned int)((unsigned long long)n * sp / SSPLIT);
    unsigned int end = s0 + (unsigned int)((unsigned long long)n * (sp + 1) / SSPLIT);
    __syncthreads();
    unsigned int i = beg + threadIdx.x;
    for (; i + 3584 < end; i += 4096) {
        unsigned long long r[8];
        #pragma unroll
        for (int k = 0; k < 8; k++) r[k] = __builtin_nontemporal_load(rec + i + k * 512);
        #pragma unroll
        for (int k = 0; k < 8; k++)
            ATOMF(&degl[((unsigned int)r[k]) >> 20], __uint_as_float((unsigned int)(r[k] >> 32)));
    }
    for (; i < end; i += 512) {
        unsigned long long r0 = __builtin_nontemporal_load(rec + i);
        ATOMF(&degl[((unsigned int)r0) >> 20], __uint_as_float((unsigned int)(r0 >> 32)));
    }
    __syncthreads();
    int node0 = b * BN;
    for (int t = threadIdx.x; t < BN; t += 512) {
        float v = degl[t];
        if (v != 0.f) ATOMF(&deg_g[node0 + t], v);
    }
}

// ---------------- node epilogue 1: dinv + y = dinv*(emb@Wc) packed block-float ----------------
__global__ __launch_bounds__(256) void node1_kernel(const float* __restrict__ deg_g,
                                                    const float* __restrict__ emb,
                                                    const float* __restrict__ w_conv,
                                                    float* __restrict__ dinv,
                                                    unsigned int* __restrict__ y) {
    int g = blockIdx.x * 256 + threadIdx.x;
    if (g >= NN) return;
    float d = deg_g[g];
    float di = d > 0.f ? rsqrtf(d) : 0.f;
    dinv[g] = di;
    float e0 = emb[3 * g], e1 = emb[3 * g + 1], e2 = emb[3 * g + 2];
    float x0 = e0 * w_conv[0] + e1 * w_conv[3] + e2 * w_conv[6];
    float x1 = e0 * w_conv[1] + e1 * w_conv[4] + e2 * w_conv[7];
    float x2 = e0 * w_conv[2] + e1 * w_conv[5] + e2 * w_conv[8];
    y[g] = pack_bf32(di * x0, di * x1, di * x2);
}

// ---------------- sweep 2: per-bucket acc in LDS (split x4), dense atomic merge ----------------
__global__ __launch_bounds__(512) void bucket_agg_kernel(const unsigned long long* __restrict__ rec,
                                                         const unsigned int* __restrict__ HG,
                                                         const unsigned int* __restrict__ y,
                                                         float* __restrict__ acc_g) {
    __shared__ float acc[BN * 3];  // 48 KB
    int b = blockIdx.x % NBUCK;
    int sp = blockIdx.x / NBUCK;
    for (int t = threadIdx.x; t < BN * 3; t += 512) acc[t] = 0.f;
    unsigned int s0 = HG[(size_t)b * NBLK];
    unsigned int e0 = HG[(size_t)(b + 1) * NBLK];
    unsigned int n = e0 - s0;
    unsigned int beg = s0 + (unsigned int)((unsigned long long)n * sp / SSPLIT);
    unsigned int end = s0 + (unsigned int)((unsigned long long)n * (sp + 1) / SSPLIT);
    __syncthreads();
    unsigned int i = beg + threadIdx.x;
    for (; i + 3584 < end; i += 4096) {
        unsigned long long r[8];
        #pragma unroll
        for (int k = 0; k < 8; k++) r[k] = __builtin_nontemporal_load(rec + i + k * 512);
        unsigned int yu[8];
        #pragma unroll
        for (int k = 0; k < 8; k++) yu[k] = y[((unsigned int)r[k]) & CMASK];
        #pragma unroll
        for (int k = 0; k < 8; k++) {
            float w = __uint_as_float((unsigned int)(r[k] >> 32));
            float3 yv = unpack_bf32(yu[k]);
            unsigned int c = (((unsigned int)r[k]) >> 20) * 3;
            ATOMF(&acc[c + 0], w * yv.x);
            ATOMF(&acc[c + 1], w * yv.y);
            ATOMF(&acc[c + 2], w * yv.z);
        }
    }
    for (; i < end; i += 512) {
        unsigned long long r0 = __builtin_nontemporal_load(rec + i);
        float w = __uint_as_float((unsigned int)(r0 >> 32));
        float3 yv = unpack_bf32(y[((unsigned int)r0) & CMASK]);
        unsigned int c = (((unsigned int)r0) >> 20) * 3;
        ATOMF(&acc[c + 0], w * yv.x);
        ATOMF(&acc[c + 1], w * yv.y);
        ATOMF(&acc[c + 2], w * yv.z);
    }
    __syncthreads();
    size_t base = (size_t)b * BN * 3;
    for (int t = threadIdx.x; t < BN * 3; t += 512) {
        float v = acc[t];
        if (v != 0.f) ATOMF(&acc_g[base + t], v);
    }
}

// ---------------- node epilogue 2: xf = leaky(dinv*acc + b_conv) packed block-float -------------
__global__ __launch_bounds__(256) void node2_kernel(const float* __restrict__ acc_g,
                                                    const float* __restrict__ dinv,
                                                    const float* __restrict__ b_conv,
                                                    unsigned int* __restrict__ xf) {
    int g = blockIdx.x * 256 + threadIdx.x;
    if (g >= NN) return;
    float di = dinv[g];
    float a0 = acc_g[3 * (size_t)g], a1 = acc_g[3 * (size_t)g + 1], a2 = acc_g[3 * (size_t)g + 2];
    xf[g] = pack_bf32(leaky(di * a0 + b_conv[0]),
                      leaky(di * a1 + b_conv[1]),
                      leaky(di * a2 + b_conv[2]));
}

// ---------------- batch MLP + column maxes ----------------
__global__ __launch_bounds__(256) void batch_kernel(const i32x4* __restrict__ home4,
                                                    const i32x4* __restrict__ away4,
                                                    const unsigned int* __restrict__ xf,
                                                    const float* __restrict__ w1,
                                                    const float* __restrict__ b1,
                                                    const float* __restrict__ w3,
                                                    const float* __restrict__ b3,
                                                    float4* __restrict__ out4,
                                                    float* __restrict__ stats, int nq) {
    int i = blockIdx.x * blockDim.x + threadIdx.x;
    float m0 = -1e30f, m1 = -1e30f, m2 = -1e30f;
    if (i < nq) {
        float W1[36], B1[6], W3[18], B3[3];
        #pragma unroll
        for (int k = 0; k < 36; k++) W1[k] = w1[k];
        #pragma unroll
        for (int k = 0; k < 6; k++) B1[k] = b1[k];
        #pragma unroll
        for (int k = 0; k < 18; k++) W3[k] = w3[k];
        #pragma unroll
        for (int k = 0; k < 3; k++) B3[k] = b3[k];

        i32x4 hh = __builtin_nontemporal_load(home4 + i);
        i32x4 aa = __builtin_nontemporal_load(away4 + i);
        int hs[4] = {hh.x, hh.y, hh.z, hh.w};
        int as_[4] = {aa.x, aa.y, aa.z, aa.w};
        float o[12];
        #pragma unroll
        for (int e = 0; e < 4; e++) {
            float3 xh = unpack_bf32(xf[hs[e]]);
            float3 xa = unpack_bf32(xf[as_[e]]);
            float h[6] = {xh.x, xh.y, xh.z, xa.x, xa.y, xa.z};
            float l1v[6];
            #pragma unroll
            for (int j = 0; j < 6; j++) {
                float s = B1[j];
                #pragma unroll
                for (int k = 0; k < 6; k++) s += h[k] * W1[k * 6 + j];
                l1v[j] = leaky(s);
            }
            float o3[3];
            #pragma unroll
            for (int j = 0; j < 3; j++) {
                float s = B3[j];
                #pragma unroll
                for (int k = 0; k < 6; k++) s += l1v[k] * W3[k * 3 + j];
                o3[j] = leaky(s);
            }
            o[3 * e + 0] = o3[0];
            o[3 * e + 1] = o3[1];
            o[3 * e + 2] = o3[2];
            m0 = fmaxf(m0, o3[0]);
            m1 = fmaxf(m1, o3[1]);
            m2 = fmaxf(m2, o3[2]);
        }
        #pragma unroll
        for (int q = 0; q < 3; q++)
            out4[3 * (size_t)i + q] = make_float4(o[4 * q], o[4 * q + 1], o[4 * q + 2], o[4 * q + 3]);
    }
    #pragma unroll
    for (int off = 32; off > 0; off >>= 1) {
        m0 = fmaxf(m0, __shfl_down(m0, off));
        m1 = fmaxf(m1, __shfl_down(m1, off));
        m2 = fmaxf(m2, __shfl_down(m2, off));
    }
    __shared__ float sm[3][4];
    int wave = threadIdx.x >> 6, lane = threadIdx.x & 63;
    if (lane == 0) { sm[0][wave] = m0; sm[1][wave] = m1; sm[2][wave] = m2; }
    __syncthreads();
    if (threadIdx.x == 0) {
        atomicMaxF(&stats[0], fmaxf(fmaxf(sm[0][0], sm[0][1]), fmaxf(sm[0][2], sm[0][3])));
        atomicMaxF(&stats[1], fmaxf(fmaxf(sm[1][0], sm[1][1]), fmaxf(sm[1][2], sm[1][3])));
        atomicMaxF(&stats[2], fmaxf(fmaxf(sm[2][0], sm[2][1]), fmaxf(sm[2][2], sm[2][3])));
    }
}

// ---------------- per-column sum of exp(v - max) ----------------
__global__ __launch_bounds__(256) void sumexp_kernel(const float4* __restrict__ out4,
                                                     float* __restrict__ stats, int nq) {
    float mx0 = stats[0], mx1 = stats[1], mx2 = stats[2];
    int i = blockIdx.x * blockDim.x + threadIdx.x;
    float s0 = 0.f, s1 = 0.f, s2 = 0.f;
    if (i < nq) {
        float4 v = out4[i];
        float vals[4] = {v.x, v.y, v.z, v.w};
        int c = (4 * i) % 3;
        #pragma unroll
        for (int e = 0; e < 4; e++) {
            float mv = (c == 0) ? mx0 : ((c == 1) ? mx1 : mx2);
            float ee = expf(vals[e] - mv);
            if (c == 0) s0 += ee; else if (c == 1) s1 += ee; else s2 += ee;
            c = (c == 2) ? 0 : (c + 1);
        }
    }
    #pragma unroll
    for (int off = 32; off > 0; off >>= 1) {
        s0 += __shfl_down(s0, off);
        s1 += __shfl_down(s1, off);
        s2 += __shfl_down(s2, off);
    }
    __shared__ float sm[3][4];
    int wave = threadIdx.x >> 6, lane = threadIdx.x & 63;
    if (lane == 0) { sm[0][wave] = s0; sm[1][wave] = s1; sm[2][wave] = s2; }
    __syncthreads();
    if (threadIdx.x == 0) {
        ATOMF(&stats[3], sm[0][0] + sm[0][1] + sm[0][2] + sm[0][3]);
        ATOMF(&stats[4], sm[1][0] + sm[1][1] + sm[1][2] + sm[1][3]);
        ATOMF(&stats[5], sm[2][0] + sm[2][1] + sm[2][2] + sm[2][3]);
    }
}

// ---------------- out = h3 - max - log(sumexp), in place ----------------
__global__ __launch_bounds__(256) void final_kernel(float4* __restrict__ out4,
                                                    const float* __restrict__ stats, int nq) {
    float o0 = stats[0] + logf(stats[3]);
    float o1 = stats[1] + logf(stats[4]);
    float o2 = stats[2] + logf(stats[5]);
    int i = blockIdx.x * blockDim.x + threadIdx.x;
    if (i >= nq) return;
    float4 v = out4[i];
    float vals[4] = {v.x, v.y, v.z, v.w};
    int c = (4 * i) % 3;
    #pragma unroll
    for (int e = 0; e < 4; e++) {
        vals[e] -= (c == 0) ? o0 : ((c == 1) ? o1 : o2);
        c = (c == 2) ? 0 : (c + 1);
    }
    out4[i] = make_float4(vals[0], vals[1], vals[2], vals[3]);
}

extern "C" void kernel_launch(void* const* d_in, const int* in_sizes, int n_in,
                              void* d_out, int out_size, void* d_ws, size_t ws_size,
                              hipStream_t stream) {
    const int*   edge_index  = (const int*)d_in[0];    // [2, NE]
    const float* edge_weight = (const float*)d_in[1];  // [NE]
    const int*   home        = (const int*)d_in[2];    // [NB]
    const int*   away        = (const int*)d_in[3];    // [NB]
    const float* emb         = (const float*)d_in[4];  // [NN,3]
    const float* w_conv      = (const float*)d_in[5];  // [3,3]
    const float* b_conv      = (const float*)d_in[6];  // [3]
    const float* w1          = (const float*)d_in[7];  // [6,6]
    const float* b1          = (const float*)d_in[8];  // [6]
    const float* w3          = (const float*)d_in[9];  // [6,3]
    const float* b3          = (const float*)d_in[10]; // [3]
    float* out = (float*)d_out;

    // workspace layout (bytes)
    char* ws = (char*)d_ws;
    uint2*        rec   = (uint2*)(ws);                        // 128,000,000
    unsigned int* HG    = (unsigned int*)(ws + 128000000);     //   1,048,576
    unsigned int* part  = (unsigned int*)(ws + 129048576);     //       1,024
    float*        deg_g = (float*)(ws + 129049600);            //   4,014,080 (245*4096*4)
    float*        dinv  = (float*)(ws + 133063680);            //   4,000,000
    unsigned int* y     = (unsigned int*)(ws + 137063680);     //   4,000,000 (block-float)
    float*        acc_g = (float*)(ws + 141063680);            //  12,042,240 (245*4096*3*4)
    unsigned int* xf    = (unsigned int*)(ws + 153105920);     //   4,000,000 (block-float)
    float*        stats = (float*)(ws + 157105920);            //          24

    const int* row = edge_index;
    const int* col = edge_index + NE;

    init_stats<<<1, 64, 0, stream>>>(stats);
    hipMemsetAsync(deg_g, 0, 4014080, stream);
    hipMemsetAsync(acc_g, 0, 12042240, stream);

    // partition edges by col>>12 into 245 buckets of 4096 nodes
    count_kernel<<<NBLK, 256, 0, stream>>>((const i32x4*)col, HG);
    scan_sum<<<NBUCKR, 256, 0, stream>>>(HG, part);
    scan_part<<<1, 256, 0, stream>>>(part);
    scan_apply<<<NBUCKR, 256, 0, stream>>>(HG, part);
    scatter_kernel<<<NBLK, 256, 0, stream>>>((const i32x4*)row, (const i32x4*)col,
                                             (const f32x4*)edge_weight, HG, rec);

    // bucketed LDS accumulation, 4 split-blocks per bucket
    bucket_deg_kernel<<<NBUCK * SSPLIT, 512, 0, stream>>>((const unsigned long long*)rec, HG, deg_g);
    node1_kernel<<<(NN + 255) / 256, 256, 0, stream>>>(deg_g, emb, w_conv, dinv, y);
    bucket_agg_kernel<<<NBUCK * SSPLIT, 512, 0, stream>>>((const unsigned long long*)rec, HG, y, acc_g);
    node2_kernel<<<(NN + 255) / 256, 256, 0, stream>>>(acc_g, dinv, b_conv, xf);

    // MLP + log-softmax over dim 0
    const int BQ = NB / 4;
    const int OQ = (NB * 3) / 4;
    batch_kernel<<<(BQ + 255) / 256, 256, 0, stream>>>((const i32x4*)home, (const i32x4*)away, xf,
                                                       w1, b1, w3, b3, (float4*)out, stats, BQ);
    sumexp_kernel<<<(OQ + 255) / 256, 256, 0, stream>>>((const float4*)out, stats, OQ);
    final_kernel<<<(OQ + 255) / 256, 256, 0, stream>>>((float4*)out, stats, OQ);
}